// Round 15
// baseline (393.265 us; speedup 1.0000x reference)
//
#include <hip/hip_runtime.h>

typedef unsigned short u16;
typedef __attribute__((ext_vector_type(8))) short short8;
typedef __attribute__((ext_vector_type(4))) float f32x4;

#define DEVFN __device__ __forceinline__

constexpr int Bc = 8, Sc = 512, Ec = 1024, Hc = 16, Dc = 64;

DEVFN u16 f2b(float f) {
  union { float f; unsigned u; } a; a.f = f;
  unsigned u = a.u;
  u += 0x7fffu + ((u >> 16) & 1u);   // RTNE to bf16
  return (u16)(u >> 16);
}
DEVFN float b2f(u16 h) {
  union { unsigned u; float f; } a; a.u = ((unsigned)h) << 16; return a.f;
}
DEVFN unsigned pack2(float a, float b) {
  return (unsigned)f2b(a) | ((unsigned)f2b(b) << 16);
}
DEVFN float wred_sum(float v) {
  #pragma unroll
  for (int o = 32; o; o >>= 1) v += __shfl_xor(v, o, 64);
  return v;
}
DEVFN void gload16(const void* g, void* l) {
  __builtin_amdgcn_global_load_lds(
      (const __attribute__((address_space(1))) void*)g,
      (__attribute__((address_space(3))) void*)l, 16, 0, 0);
}

// ---------------------------------------------------------------------------
// Weight pre-conversion: 18 matrices of 1024x1024 f32 -> bf16
// ---------------------------------------------------------------------------
struct PtrBundle { const float* src[18]; u16* dst[18]; };

__global__ __launch_bounds__(256) void cvtw_kernel(PtrBundle pb)
{
  int w = blockIdx.y;
  int i = blockIdx.x * 256 + threadIdx.x;
  float4 v = ((const float4*)pb.src[w])[i];
  uint2 o; o.x = pack2(v.x, v.y); o.y = pack2(v.z, v.w);
  ((uint2*)pb.dst[w])[i] = o;
}

// ---------------------------------------------------------------------------
// Fused GEMM: C[M,N] = A@W1^T (+ A2@W2^T), A bf16 [M,1024], W bf16 [1024,1024].
// 64x64 tile, BK=32, 256 thr / 4 waves (2x2, wave 32x32), depth-2 counted
// vmcnt, 3-buffer rotation, LDS 24KB -> 6 blocks/CU resident where grid
// allows. T2 swizzle (linear LDS dest + pre-swizzled global source chunk +
// XOR'd read offset -> bank conflicts = 0). Natural block order (no remap).
// A through LDS (R13: scattered per-lane A loads are 2.5x worse than
// coalesced global_load_lds staging).
// epi: 0 b16 row-major | 1 Q-frag (qu,qv scaled 1/8) | 2 b16 preact | 3 rx |
//      4 combine | 5 relu | 6 VT-frag | 7 K-frag | 8 R-frag
// ---------------------------------------------------------------------------
struct GemmSeg {
  const u16* A1; const u16* A2;      // A2 != null -> dual-K (K=2048)
  const u16* W1; const u16* W2;
  const float* bias;
  const float* bu; const float* bv;  // epi 1
  const u16* xB;                     // epi 3: bf16 x input
  const float* xF;                   // epi 4: f32 x input
  const u16* zB;                     // epi 4: bf16 z-preact
  u16* o16a; u16* o16b;
  float* oF;
  int epi;
};
struct GemmDesc { GemmSeg seg[3]; };

__global__ __launch_bounds__(256) void gemm_f(GemmDesc dd)
{
  __shared__ u16 lA[3][64 * 32];
  __shared__ u16 lB[3][64 * 32];
  const int tid = threadIdx.x;

  const GemmSeg s = dd.seg[blockIdx.y >> 4];
  const int n0 = (blockIdx.y & 15) * 64;
  const int m0 = blockIdx.x * 64;
  const int wid = tid >> 6, lane = tid & 63;
  const int wm = (wid >> 1) * 32, wn = (wid & 1) * 32;
  const int c15 = lane & 15, g = lane >> 4;
  const int arow = tid >> 2;
  const int ac8 = (((tid & 3) ^ ((tid >> 3) & 3))) * 8;   // swizzled source chunk
  const int gs8 = (g ^ ((c15 >> 1) & 3)) * 8;             // swizzled read offset

  f32x4 acc[2][2];
  #pragma unroll
  for (int mi = 0; mi < 2; ++mi)
    #pragma unroll
    for (int ni = 0; ni < 2; ++ni) acc[mi][ni] = {0.f, 0.f, 0.f, 0.f};

  const int nst = (s.A2 ? 2 : 1) * 32;   // K-steps of 32

  auto stage = [&](int buf, int st) {
    int sg = st >> 5, k0 = (st & 31) << 5;
    const u16* Abase = (sg ? s.A2 : s.A1) + (size_t)m0 * 1024;
    const u16* Wbase = (sg ? s.W2 : s.W1) + (size_t)n0 * 1024;
    gload16(Abase + (size_t)arow * 1024 + k0 + ac8, &lA[buf][tid * 8]);
    gload16(Wbase + (size_t)arow * 1024 + k0 + ac8, &lB[buf][tid * 8]);
  };

  // prologue: 2 tiles in flight
  stage(0, 0);
  stage(1, 1);

  for (int st = 0; st < nst; ++st) {
    const int cur = st % 3;
    if (st + 1 < nst) asm volatile("s_waitcnt vmcnt(2)" ::: "memory");
    else              asm volatile("s_waitcnt vmcnt(0)" ::: "memory");
    __builtin_amdgcn_s_barrier();
    __builtin_amdgcn_sched_barrier(0);

    short8 afr[2], bfr[2];
    #pragma unroll
    for (int mi = 0; mi < 2; ++mi)
      afr[mi] = *(const short8*)&lA[cur][(wm + mi * 16 + c15) * 32 + gs8];
    #pragma unroll
    for (int ni = 0; ni < 2; ++ni)
      bfr[ni] = *(const short8*)&lB[cur][(wn + ni * 16 + c15) * 32 + gs8];

    // WAR-safe: buf (st+2)%3 was last read at step st-1; those ds_reads
    // completed (lgkm wait before MFMA) before each wave's step-st barrier.
    if (st + 2 < nst) stage((st + 2) % 3, st + 2);

    #pragma unroll
    for (int mi = 0; mi < 2; ++mi)
      #pragma unroll
      for (int ni = 0; ni < 2; ++ni)
        acc[mi][ni] = __builtin_amdgcn_mfma_f32_16x16x32_bf16(
            afr[mi], bfr[ni], acc[mi][ni], 0, 0, 0);
  }

  const int colb = n0 + wn + c15;
  const int rowb = m0 + wm + (lane >> 4) * 4;
  #pragma unroll
  for (int ni = 0; ni < 2; ++ni) {
    int col = colb + ni * 16;
    float bb = s.bias ? s.bias[col] : 0.f;
    float bu = 0.f, bvv = 0.f;
    if (s.epi == 1) { bu = s.bu[col]; bvv = s.bv[col]; }
    // fragment decompositions of col
    int hI = col >> 6, dI = col & 63;
    int kcd = (dI >> 5) & 1, gd = (dI >> 3) & 3, ed = dI & 7;   // d as k-dim
    int ntd = dI >> 4, c15d = dI & 15;                          // d as row-dim
    #pragma unroll
    for (int mi = 0; mi < 2; ++mi) {
      int row0 = rowb + mi * 16;
      size_t off0 = (size_t)row0 * 1024 + col;
      float v4[4];
      #pragma unroll
      for (int q = 0; q < 4; ++q) v4[q] = acc[mi][ni][q] + bb;
      switch (s.epi) {
        case 0:
          #pragma unroll
          for (int q = 0; q < 4; ++q) s.o16a[off0 + (size_t)q * 1024] = f2b(v4[q]);
          break;
        case 1:
          #pragma unroll
          for (int q = 0; q < 4; ++q) {
            int ri = row0 + q;
            size_t off = ((size_t)hI << 18) +
                         (((size_t)(((ri >> 4) * 2 + kcd) * 16 + (ri & 15)) * 4 + gd) << 3) + ed;
            s.o16a[off] = f2b((v4[q] + bu)  * 0.125f);
            s.o16b[off] = f2b((v4[q] + bvv) * 0.125f);
          }
          break;
        case 2:
          #pragma unroll
          for (int q = 0; q < 4; ++q) s.o16a[off0 + (size_t)q * 1024] = f2b(v4[q]);
          break;
        case 3:
          #pragma unroll
          for (int q = 0; q < 4; ++q) {
            size_t off = off0 + (size_t)q * 1024;
            float sg1 = 1.f / (1.f + __expf(-v4[q]));
            s.o16a[off] = f2b(sg1 * b2f(s.xB[off]));
          }
          break;
        case 4:
          #pragma unroll
          for (int q = 0; q < 4; ++q) {
            size_t off = off0 + (size_t)q * 1024;
            float z = 1.f / (1.f + __expf(-(b2f(s.zB[off]) - 2.f)));
            float r = (1.f - z) * s.xF[off] + z * tanhf(v4[q]);
            s.oF[off] = r;
            if (s.o16a) s.o16a[off] = f2b(r);
          }
          break;
        case 5:
          #pragma unroll
          for (int q = 0; q < 4; ++q) s.o16a[off0 + (size_t)q * 1024] = f2b(fmaxf(v4[q], 0.f));
          break;
        case 6: {
          // VT-frag: row0..row0+3 are consecutive j (same kc/g octet)
          int bI = row0 >> 9, j = row0 & 511;
          int kt = j >> 6, jj = j & 63;
          int kcj = jj >> 5, gj = (jj >> 3) & 3, e0 = jj & 7;
          size_t off = ((size_t)((bI * 16 + hI) * 8 + kt) << 12) +
                       (((size_t)((ntd * 2 + kcj) * 16 + c15d) * 4 + gj) << 3) + e0;
          uint2 o; o.x = pack2(v4[0], v4[1]); o.y = pack2(v4[2], v4[3]);
          *(uint2*)(s.o16a + off) = o;
        } break;
        case 7:
          #pragma unroll
          for (int q = 0; q < 4; ++q) {
            int rj = row0 + q;
            int bI = rj >> 9, kt = (rj >> 6) & 7, jr = rj & 63;
            size_t off = ((size_t)((bI * 16 + hI) * 8 + kt) << 12) +
                         (((size_t)(((jr >> 4) * 2 + kcd) * 16 + (jr & 15)) * 4 + gd) << 3) + ed;
            s.o16a[off] = f2b(v4[q]);
          }
          break;
        case 8:
          #pragma unroll
          for (int q = 0; q < 4; ++q) {
            int t = row0 + q;
            size_t off = ((size_t)hI << 14) +
                         (((size_t)(((t >> 4) * 2 + kcd) * 16 + (t & 15)) * 4 + gd) << 3) + ed;
            s.o16a[off] = f2b(v4[q]);
          }
          break;
      }
    }
  }
}

// ---------------------------------------------------------------------------
// LayerNorm over rows of 1024, fp32 in -> bf16 out (+ optional raw bf16 copy)
// Fused q/k variant: blockIdx.x in [0,8192): rows 0..4095 = x1, 4096.. = x2.
// ---------------------------------------------------------------------------
__global__ __launch_bounds__(256) void ln_kernel(
    const float* __restrict__ x1, const float* __restrict__ x2,
    const float* __restrict__ g, const float* __restrict__ bb,
    u16* __restrict__ out1p, u16* __restrict__ out2p,
    u16* __restrict__ raw1)
{
  const int blk = blockIdx.x, t = threadIdx.x;
  const int row = blk & 4095;
  const bool second = blk >= 4096;
  const float* x = second ? x2 : x1;
  u16* out = second ? out2p : out1p;
  float4 xv = ((const float4*)x)[(size_t)row * 256 + t];
  float s  = xv.x + xv.y + xv.z + xv.w;
  float s2 = xv.x * xv.x + xv.y * xv.y + xv.z * xv.z + xv.w * xv.w;
  s = wred_sum(s); s2 = wred_sum(s2);
  __shared__ float sh[8];
  int wid = t >> 6, lane = t & 63;
  if (lane == 0) { sh[wid] = s; sh[4 + wid] = s2; }
  __syncthreads();
  s  = sh[0] + sh[1] + sh[2] + sh[3];
  s2 = sh[4] + sh[5] + sh[6] + sh[7];
  float mean = s * (1.f / 1024.f);
  float var  = s2 * (1.f / 1024.f) - mean * mean;
  float rstd = rsqrtf(var + 1e-5f);
  float4 gv = ((const float4*)g)[t];
  float4 bv = ((const float4*)bb)[t];
  uint2 o;
  o.x = pack2((xv.x - mean) * rstd * gv.x + bv.x,
              (xv.y - mean) * rstd * gv.y + bv.y);
  o.y = pack2((xv.z - mean) * rstd * gv.z + bv.z,
              (xv.w - mean) * rstd * gv.w + bv.w);
  *(uint2*)&out[(size_t)row * 1024 + t * 4] = o;
  if (!second && raw1) {
    uint2 o2; o2.x = pack2(xv.x, xv.y); o2.y = pack2(xv.z, xv.w);
    *(uint2*)&raw1[(size_t)row * 1024 + t * 4] = o2;
  }
}

__global__ __launch_bounds__(256) void posenc_kernel(u16* __restrict__ out)
{
  int idx = blockIdx.x * 256 + threadIdx.x;   // 0..262143
  int i = idx >> 9, f = idx & 511;
  float pos = (float)(Sc - 1 - i);
  float invf = expf((float)f * -0.017988946039016f);
  float ang = pos * invf;
  out[(size_t)i * 1024 + f]       = f2b(sinf(ang));
  out[(size_t)i * 1024 + 512 + f] = f2b(cosf(ang));
}

// ---------------------------------------------------------------------------
// MFMA flash attention, balanced q-tile pairing {x, 7-x}, double-buffered
// async LDS staging of fragment-ordered K/VT tiles (T2-swizzled), qu/qv
// pre-scaled 1/8.
// ---------------------------------------------------------------------------
__global__ __launch_bounds__(256) void attn_mfma(
    const u16* __restrict__ quF, const u16* __restrict__ qvF,
    const u16* __restrict__ PK, const u16* __restrict__ PVT,
    const u16* __restrict__ RF, u16* __restrict__ out)
{
  __shared__ u16 lK[2][4096];
  __shared__ u16 lVT[2][4096];
  __shared__ u16 PW[4][16 * 72];

  const int tid = threadIdx.x;
  const int wave = tid >> 6, lane = tid & 63;
  const int g = lane >> 4, c15 = lane & 15;
  const int x = blockIdx.x;            // 0..3
  const int h = blockIdx.y, b = blockIdx.z;
  const int qA = x, qB = 7 - x;

  const size_t pkbase = (size_t)(b * 16 + h) << 15;   // 8 tiles * 4096 u16
  const size_t qhead  = (size_t)h << 18;
  const size_t rhead  = (size_t)h << 14;
  const size_t bh_off = ((size_t)b * Sc) * Ec + h * Dc;
  const int fchunk  = (c15 * 4 + g) * 8;                          // global frag offset
  const int fchunkS = (c15 * 4 + (g ^ ((c15 >> 1) & 3))) * 8;     // LDS swizzled read
  const int src8 = (tid ^ ((tid >> 3) & 3)) * 8;                  // swizzled stage src

  u16* pw = PW[wave];

  auto stage = [&](int buf, int kt) {
    const u16* ks = PK  + pkbase + ((size_t)kt << 12);
    const u16* vs = PVT + pkbase + ((size_t)kt << 12);
    gload16(ks + src8,        &lK[buf][tid * 8]);
    gload16(ks + 2048 + src8, &lK[buf][2048 + tid * 8]);
    gload16(vs + src8,        &lVT[buf][tid * 8]);
    gload16(vs + 2048 + src8, &lVT[buf][2048 + tid * 8]);
  };

  short8 qa[2], va[2];
  int i0w = qA * 64 + wave * 16;
  {
    int i16g = b * 32 + (i0w >> 4);
    #pragma unroll
    for (int kc = 0; kc < 2; ++kc) {
      size_t off = qhead + ((size_t)(i16g * 2 + kc) * 64) * 8 + fchunk;
      qa[kc] = *(const short8*)(quF + off);
      va[kc] = *(const short8*)(qvF + off);
    }
  }

  f32x4 oacc[4];
  #pragma unroll
  for (int t = 0; t < 4; ++t) oacc[t] = {0.f, 0.f, 0.f, 0.f};
  float m[4], l[4];
  #pragma unroll
  for (int q = 0; q < 4; ++q) { m[q] = -1e30f; l[q] = 0.f; }

  stage(0, 0);
  asm volatile("s_waitcnt vmcnt(0)" ::: "memory");
  __syncthreads();

  for (int s2 = 0; s2 < 9; ++s2) {
    const int buf = s2 & 1;
    const int kt = (s2 <= x) ? s2 : (s2 - x - 1);
    const int j0 = kt * 64;
    if (s2 < 8) {
      int ns = s2 + 1;
      stage(buf ^ 1, (ns <= x) ? ns : (ns - x - 1));
    }

    // ---- AC = (q+u)/8 K^T ----
    f32x4 ac[4];
    #pragma unroll
    for (int t = 0; t < 4; ++t) ac[t] = {0.f, 0.f, 0.f, 0.f};
    __builtin_amdgcn_s_setprio(1);
    #pragma unroll
    for (int kc = 0; kc < 2; ++kc)
      #pragma unroll
      for (int nt = 0; nt < 4; ++nt) {
        short8 kb = *(const short8*)&lK[buf][(nt * 2 + kc) * 512 + fchunkS];
        ac[nt] = __builtin_amdgcn_mfma_f32_16x16x32_bf16(qa[kc], kb, ac[nt], 0, 0, 0);
      }

    // ---- E band = (q+vb)/8 R^T ----
    const int t016 = (496 - i0w + j0) >> 4;
    f32x4 e5[5];
    #pragma unroll
    for (int t = 0; t < 5; ++t) e5[t] = {0.f, 0.f, 0.f, 0.f};
    #pragma unroll
    for (int kc = 0; kc < 2; ++kc)
      #pragma unroll
      for (int nt = 0; nt < 5; ++nt) {
        int t16 = t016 + nt; t16 = t16 > 31 ? 31 : t16;
        short8 rb = *(const short8*)(RF + rhead + (size_t)(t16 * 2 + kc) * 512 + fchunk);
        e5[nt] = __builtin_amdgcn_mfma_f32_16x16x32_bf16(va[kc], rb, e5[nt], 0, 0, 0);
      }
    __builtin_amdgcn_s_setprio(0);

    // ---- rel-shift rotate within 16-lane groups ----
    float rot[5][4];
    #pragma unroll
    for (int q = 0; q < 4; ++q) {
      int src = (lane & 48) | ((15 - (g * 4 + q) + c15) & 15);
      #pragma unroll
      for (int nt = 0; nt < 5; ++nt)
        rot[nt][q] = __shfl(e5[nt][q], src, 64);
    }

    // ---- combine + causal mask ----
    float s[4][4];
    #pragma unroll
    for (int ct = 0; ct < 4; ++ct) {
      int jcol = j0 + ct * 16 + c15;
      #pragma unroll
      for (int q = 0; q < 4; ++q) {
        int r = g * 4 + q;
        int u = 15 - r + c15;
        float bd = (u >> 4) ? rot[ct + 1][q] : rot[ct][q];
        float sv = ac[ct][q] + bd;
        s[ct][q] = (jcol <= i0w + r) ? sv : -1e30f;
      }
    }

    // ---- online softmax ----
    float mnew[4], csc[4];
    #pragma unroll
    for (int q = 0; q < 4; ++q) {
      float mx = fmaxf(fmaxf(s[0][q], s[1][q]), fmaxf(s[2][q], s[3][q]));
      #pragma unroll
      for (int o = 8; o; o >>= 1) mx = fmaxf(mx, __shfl_xor(mx, o, 64));
      mnew[q] = fmaxf(m[q], mx);
      csc[q] = __expf(m[q] - mnew[q]);
      m[q] = mnew[q];
    }
    float rs[4] = {0.f, 0.f, 0.f, 0.f};
    float p[4][4];
    #pragma unroll
    for (int ct = 0; ct < 4; ++ct)
      #pragma unroll
      for (int q = 0; q < 4; ++q) {
        p[ct][q] = __expf(s[ct][q] - mnew[q]);
        rs[q] += p[ct][q];
      }
    #pragma unroll
    for (int q = 0; q < 4; ++q) {
      float t = rs[q];
      #pragma unroll
      for (int o = 8; o; o >>= 1) t += __shfl_xor(t, o, 64);
      l[q] = l[q] * csc[q] + t;
      #pragma unroll
      for (int ct = 0; ct < 4; ++ct) oacc[ct][q] *= csc[q];
    }

    // ---- P -> bf16 via per-wave LDS transpose (wave-local) ----
    #pragma unroll
    for (int ct = 0; ct < 4; ++ct)
      #pragma unroll
      for (int q = 0; q < 4; ++q)
        pw[(g * 4 + q) * 72 + ct * 16 + c15] = f2b(p[ct][q]);

    // ---- PV from staged VT ----
    __builtin_amdgcn_s_setprio(1);
    #pragma unroll
    for (int kc = 0; kc < 2; ++kc) {
      short8 pa = *(const short8*)&pw[c15 * 72 + kc * 32 + g * 8];
      #pragma unroll
      for (int nt = 0; nt < 4; ++nt) {
        short8 vb8 = *(const short8*)&lVT[buf][(nt * 2 + kc) * 512 + fchunkS];
        oacc[nt] = __builtin_amdgcn_mfma_f32_16x16x32_bf16(pa, vb8, oacc[nt], 0, 0, 0);
      }
    }
    __builtin_amdgcn_s_setprio(0);

    // ---- phase switch: write q-tile A, reset for B ----
    if (s2 == x) {
      #pragma unroll
      for (int q = 0; q < 4; ++q) {
        float rl = 1.f / l[q];
        size_t ro = bh_off + (size_t)(i0w + g * 4 + q) * Ec;
        #pragma unroll
        for (int ct = 0; ct < 4; ++ct)
          out[ro + ct * 16 + c15] = f2b(oacc[ct][q] * rl);
      }
      i0w = qB * 64 + wave * 16;
      int i16g = b * 32 + (i0w >> 4);
      #pragma unroll
      for (int kc = 0; kc < 2; ++kc) {
        size_t off = qhead + ((size_t)(i16g * 2 + kc) * 64) * 8 + fchunk;
        qa[kc] = *(const short8*)(quF + off);
        va[kc] = *(const short8*)(qvF + off);
      }
      #pragma unroll
      for (int t = 0; t < 4; ++t) oacc[t] = {0.f, 0.f, 0.f, 0.f};
      #pragma unroll
      for (int q = 0; q < 4; ++q) { m[q] = -1e30f; l[q] = 0.f; }
    }

    asm volatile("s_waitcnt vmcnt(0)" ::: "memory");
    __syncthreads();
  }

  // ---- write q-tile B ----
  #pragma unroll
  for (int q = 0; q < 4; ++q) {
    float rl = 1.f / l[q];
    size_t ro = bh_off + (size_t)(i0w + g * 4 + q) * Ec;
    #pragma unroll
    for (int ct = 0; ct < 4; ++ct)
      out[ro + ct * 16 + c15] = f2b(oacc[ct][q] * rl);
  }
}

// ---------------------------------------------------------------------------
extern "C" void kernel_launch(void* const* d_in, const int* in_sizes, int n_in,
                              void* d_out, int out_size, void* d_ws, size_t ws_size,
                              hipStream_t stream) {
  (void)in_sizes; (void)n_in; (void)out_size; (void)ws_size;

  const float* query = (const float*)d_in[0];
  const float* key   = (const float*)d_in[1];
  const float* ln1_g = (const float*)d_in[4];
  const float* ln1_b = (const float*)d_in[5];
  const float* ln2_g = (const float*)d_in[6];
  const float* ln2_b = (const float*)d_in[7];
  const float* Wq = (const float*)d_in[8];   const float* bq = (const float*)d_in[9];
  const float* Wk = (const float*)d_in[10];  const float* bk = (const float*)d_in[11];
  const float* Wv = (const float*)d_in[12];  const float* bv_in = (const float*)d_in[13];
  const float* Wp = (const float*)d_in[14];
  const float* Wo = (const float*)d_in[15];  const float* bo = (const float*)d_in[16];
  const float* u_bias = (const float*)d_in[17];
  const float* v_bias = (const float*)d_in[18];
  const float* fc_W = (const float*)d_in[31]; const float* fc_b = (const float*)d_in[32];

  const size_t MB = 1ull << 20;
  char* ws = (char*)d_ws;
  u16* wb[18];
  for (int i = 0; i < 18; ++i) wb[i] = (u16*)(ws + (size_t)i * 2 * MB);
  u16*   normq16 = (u16*)(ws + 36 * MB);  // -> att16 -> rx16
  u16*   normk16 = (u16*)(ws + 44 * MB);  // -> Y16
  u16*   xq16    = (u16*)(ws + 52 * MB);  // -> ln2o16
  u16*   pos16   = (u16*)(ws + 60 * MB);
  u16*   rF16    = (u16*)(ws + 61 * MB);  // R fragment layout (512KB)
  u16*   quF16   = (u16*)(ws + 62 * MB);  // -> out116
  u16*   qvF16   = (u16*)(ws + 70 * MB);  // -> Ef16
  u16*   pk16    = (u16*)(ws + 78 * MB);  // \ -> tB16 (8MB)
  u16*   pvt16   = (u16*)(ws + 86 * MB);  // /
  float* out1    = (float*)(ws + 94 * MB);// 16MB
  u16*   att16   = normq16;
  u16*   Y16     = normk16;
  u16*   rx16    = normq16;
  u16*   out116  = quF16;
  u16*   Ef16    = qvF16;
  u16*   ln2o16  = xq16;
  u16*   tB16    = pk16;

  // --- weight conversion ---
  PtrBundle pb;
  const float* wsrc[18] = {Wq, Wk, Wv, Wp, Wo, fc_W,
                           (const float*)d_in[19], (const float*)d_in[20],
                           (const float*)d_in[21], (const float*)d_in[22],
                           (const float*)d_in[23], (const float*)d_in[24],
                           (const float*)d_in[25], (const float*)d_in[26],
                           (const float*)d_in[27], (const float*)d_in[28],
                           (const float*)d_in[29], (const float*)d_in[30]};
  for (int i = 0; i < 18; ++i) { pb.src[i] = wsrc[i]; pb.dst[i] = wb[i]; }
  cvtw_kernel<<<dim3(1024, 18), 256, 0, stream>>>(pb);

  // --- stage 1 (fused q/k LN; query LN also emits raw bf16 copy -> xq16) ---
  ln_kernel<<<8192, 256, 0, stream>>>(query, key, ln1_g, ln1_b,
                                      normq16, normk16, xq16);
  posenc_kernel<<<1024, 256, 0, stream>>>(pos16);

  GemmSeg z{}; GemmDesc d;

  // --- QKV fused (grid 64x48, 6 blocks/CU resident) ---
  d.seg[0] = z; d.seg[0].A1 = normq16; d.seg[0].W1 = wb[0]; d.seg[0].bias = bq;
  d.seg[0].bu = u_bias; d.seg[0].bv = v_bias;
  d.seg[0].o16a = quF16; d.seg[0].o16b = qvF16; d.seg[0].epi = 1;
  d.seg[1] = z; d.seg[1].A1 = normk16; d.seg[1].W1 = wb[1]; d.seg[1].bias = bk;
  d.seg[1].o16a = pk16; d.seg[1].epi = 7;
  d.seg[2] = z; d.seg[2].A1 = normk16; d.seg[2].W1 = wb[2]; d.seg[2].bias = bv_in;
  d.seg[2].o16a = pvt16; d.seg[2].epi = 6;
  gemm_f<<<dim3(64, 48), 256, 0, stream>>>(d);

  // --- Wp (M=512, grid 8x16) -> R fragment layout ---
  d.seg[0] = z; d.seg[0].A1 = pos16; d.seg[0].W1 = wb[3];
  d.seg[0].o16a = rF16; d.seg[0].epi = 8;
  gemm_f<<<dim3(8, 16), 256, 0, stream>>>(d);

  // --- attention (balanced pairing, grid 4x16x8) ---
  attn_mfma<<<dim3(4, 16, 8), 256, 0, stream>>>(quF16, qvF16, pk16, pvt16,
                                                rF16, att16);

  // --- Wo (grid 64x16, 4 blocks/CU) ---
  d.seg[0] = z; d.seg[0].A1 = att16; d.seg[0].W1 = wb[4]; d.seg[0].bias = bo;
  d.seg[0].o16a = Y16; d.seg[0].epi = 0;
  gemm_f<<<dim3(64, 16), 256, 0, stream>>>(d);

  // --- gate1 r+z (dual-K, grid 64x32, 6 blocks/CU resident) ---
  d.seg[0] = z; d.seg[0].A1 = Y16; d.seg[0].A2 = xq16;
  d.seg[0].W1 = wb[6]; d.seg[0].W2 = wb[7];
  d.seg[0].xB = xq16; d.seg[0].o16a = rx16; d.seg[0].epi = 3;
  d.seg[1] = z; d.seg[1].A1 = Y16; d.seg[1].A2 = xq16;
  d.seg[1].W1 = wb[8]; d.seg[1].W2 = wb[9];
  d.seg[1].o16a = tB16; d.seg[1].epi = 2;
  gemm_f<<<dim3(64, 32), 256, 0, stream>>>(d);

  // --- gate1 g + combine (dual-K, grid 64x16) ---
  d.seg[0] = z; d.seg[0].A1 = Y16; d.seg[0].A2 = rx16;
  d.seg[0].W1 = wb[10]; d.seg[0].W2 = wb[11];
  d.seg[0].xF = query; d.seg[0].zB = tB16;
  d.seg[0].oF = out1; d.seg[0].o16a = out116; d.seg[0].epi = 4;
  gemm_f<<<dim3(64, 16), 256, 0, stream>>>(d);

  // --- FFN ---
  ln_kernel<<<4096, 256, 0, stream>>>(out1, nullptr, ln2_g, ln2_b,
                                      ln2o16, nullptr, nullptr);
  d.seg[0] = z; d.seg[0].A1 = ln2o16; d.seg[0].W1 = wb[5]; d.seg[0].bias = fc_b;
  d.seg[0].o16a = Ef16; d.seg[0].epi = 5;
  gemm_f<<<dim3(64, 16), 256, 0, stream>>>(d);

  // --- gate2 r+z (dual-K, grid 64x32) ---
  d.seg[0] = z; d.seg[0].A1 = Ef16; d.seg[0].A2 = out116;
  d.seg[0].W1 = wb[12]; d.seg[0].W2 = wb[13];
  d.seg[0].xB = out116; d.seg[0].o16a = rx16; d.seg[0].epi = 3;
  d.seg[1] = z; d.seg[1].A1 = Ef16; d.seg[1].A2 = out116;
  d.seg[1].W1 = wb[14]; d.seg[1].W2 = wb[15];
  d.seg[1].o16a = tB16; d.seg[1].epi = 2;
  gemm_f<<<dim3(64, 32), 256, 0, stream>>>(d);

  // --- gate2 g + final combine (dual-K, grid 64x16) ---
  d.seg[0] = z; d.seg[0].A1 = Ef16; d.seg[0].A2 = rx16;
  d.seg[0].W1 = wb[16]; d.seg[0].W2 = wb[17];
  d.seg[0].xF = out1; d.seg[0].zB = tB16;
  d.seg[0].oF = (float*)d_out; d.seg[0].epi = 4;
  gemm_f<<<dim3(64, 16), 256, 0, stream>>>(d);
}

// Round 16
// 326.123 us; speedup vs baseline: 1.2059x; 1.2059x over previous
//
#include <hip/hip_runtime.h>

typedef unsigned short u16;
typedef __attribute__((ext_vector_type(8))) short short8;
typedef __attribute__((ext_vector_type(4))) float f32x4;

#define DEVFN __device__ __forceinline__

constexpr int Bc = 8, Sc = 512, Ec = 1024, Hc = 16, Dc = 64;

DEVFN u16 f2b(float f) {
  union { float f; unsigned u; } a; a.f = f;
  unsigned u = a.u;
  u += 0x7fffu + ((u >> 16) & 1u);   // RTNE to bf16
  return (u16)(u >> 16);
}
DEVFN float b2f(u16 h) {
  union { unsigned u; float f; } a; a.u = ((unsigned)h) << 16; return a.f;
}
DEVFN unsigned pack2(float a, float b) {
  return (unsigned)f2b(a) | ((unsigned)f2b(b) << 16);
}
DEVFN float wred_sum(float v) {
  #pragma unroll
  for (int o = 32; o; o >>= 1) v += __shfl_xor(v, o, 64);
  return v;
}
DEVFN void gload16(const void* g, void* l) {
  __builtin_amdgcn_global_load_lds(
      (const __attribute__((address_space(1))) void*)g,
      (__attribute__((address_space(3))) void*)l, 16, 0, 0);
}

// ---------------------------------------------------------------------------
// Weight pre-conversion: 18 matrices of 1024x1024 f32 -> bf16
// ---------------------------------------------------------------------------
struct PtrBundle { const float* src[18]; u16* dst[18]; };

__global__ __launch_bounds__(256) void cvtw_kernel(PtrBundle pb)
{
  int w = blockIdx.y;
  int i = blockIdx.x * 256 + threadIdx.x;
  float4 v = ((const float4*)pb.src[w])[i];
  uint2 o; o.x = pack2(v.x, v.y); o.y = pack2(v.z, v.w);
  ((uint2*)pb.dst[w])[i] = o;
}

// ---------------------------------------------------------------------------
// Fused GEMM: C[M,N] = A@W1^T (+ A2@W2^T), A bf16 [M,1024], W bf16 [1024,1024].
// TMxTN tile, BK=32, counted-vmcnt multi-buffer pipeline, T2 swizzle
// (linear LDS dest + pre-swizzled global source chunk + XOR'd read offset ->
// bank conflicts = 0). Natural block order (no remap: keeps per-XCD A/W
// working set cache-resident). A goes through LDS — R13 taught us the
// coalesced global_load_lds staging beats scattered per-lane A loads by 2.5x.
// R15 taught us TM=TN=64 everywhere loses 20% (W re-fetch doubles, per-step
// overhead amortization halves) — keep the mixed 128/64 configuration.
//   TM=128,TN=128: 512 thr / 8 waves (2M x 4N, wave 64x32), depth-2, 3 bufs.
//   TM= 64,TN= 64: 256 thr / 4 waves (2M x 2N, wave 32x32), depth-3, 4 bufs;
//                  grid.x = M/64 -> 4 blocks/CU on single-seg dispatches.
// epi: 0 b16 row-major | 1 Q-frag (qu,qv scaled 1/8) | 2 b16 preact | 3 rx |
//      4 combine | 5 relu | 6 VT-frag | 7 K-frag | 8 R-frag
// ---------------------------------------------------------------------------
struct GemmSeg {
  const u16* A1; const u16* A2;      // A2 != null -> dual-K (K=2048)
  const u16* W1; const u16* W2;
  const float* bias;
  const float* bu; const float* bv;  // epi 1
  const u16* xB;                     // epi 3: bf16 x input
  const float* xF;                   // epi 4: f32 x input
  const u16* zB;                     // epi 4: bf16 z-preact
  u16* o16a; u16* o16b;
  float* oF;
  int epi;
};
struct GemmDesc { GemmSeg seg[3]; };

template<int TM, int TN>
__global__ __launch_bounds__(TM == 128 ? 512 : 256) void gemm_f(GemmDesc dd)
{
  constexpr int MI = TM / 32;              // 4 (TM=128) | 2 (TM=64)
  constexpr int D = (TM == 128) ? 2 : 3;   // prefetch depth
  constexpr int NBUF = D + 1;
  constexpr int BPS = 1024 / TN;
  __shared__ u16 lA[NBUF][TM * 32];
  __shared__ u16 lB[NBUF][TN * 32];
  const int tid = threadIdx.x;

  const GemmSeg s = dd.seg[blockIdx.y / BPS];
  const int n0 = (blockIdx.y % BPS) * TN;
  const int m0 = blockIdx.x * TM;
  const int wid = tid >> 6, lane = tid & 63;
  int wm, wn;
  if constexpr (TM == 128) { wm = (wid >> 2) * 64; wn = (wid & 3) * 32; }
  else                     { wm = (wid >> 1) * 32; wn = (wid & 1) * 32; }
  const int c15 = lane & 15, g = lane >> 4;
  const int arow = tid >> 2;
  const int ac8 = (((tid & 3) ^ ((tid >> 3) & 3))) * 8;   // swizzled source chunk
  const int gs8 = (g ^ ((c15 >> 1) & 3)) * 8;             // swizzled read offset

  f32x4 acc[MI][2];
  #pragma unroll
  for (int mi = 0; mi < MI; ++mi)
    #pragma unroll
    for (int ni = 0; ni < 2; ++ni) acc[mi][ni] = {0.f, 0.f, 0.f, 0.f};

  const int nst = (s.A2 ? 2 : 1) * 32;   // K-steps of 32

  auto stage = [&](int buf, int st) {
    int sg = st >> 5, k0 = (st & 31) << 5;
    const u16* Abase = (sg ? s.A2 : s.A1) + (size_t)m0 * 1024;
    const u16* Wbase = (sg ? s.W2 : s.W1) + (size_t)n0 * 1024;
    gload16(Abase + (size_t)arow * 1024 + k0 + ac8, &lA[buf][tid * 8]);
    gload16(Wbase + (size_t)arow * 1024 + k0 + ac8, &lB[buf][tid * 8]);
  };

  // prologue: D tiles in flight
  #pragma unroll
  for (int p = 0; p < D; ++p) stage(p, p);

  for (int st = 0; st < nst; ++st) {
    const int cur = st % NBUF;
    if constexpr (D == 2) {
      if (st + 1 < nst) asm volatile("s_waitcnt vmcnt(2)" ::: "memory");
      else              asm volatile("s_waitcnt vmcnt(0)" ::: "memory");
    } else {
      if (st + 2 < nst)      asm volatile("s_waitcnt vmcnt(4)" ::: "memory");
      else if (st + 1 < nst) asm volatile("s_waitcnt vmcnt(2)" ::: "memory");
      else                   asm volatile("s_waitcnt vmcnt(0)" ::: "memory");
    }
    __builtin_amdgcn_s_barrier();
    __builtin_amdgcn_sched_barrier(0);

    short8 afr[MI], bfr[2];
    #pragma unroll
    for (int mi = 0; mi < MI; ++mi)
      afr[mi] = *(const short8*)&lA[cur][(wm + mi * 16 + c15) * 32 + gs8];
    #pragma unroll
    for (int ni = 0; ni < 2; ++ni)
      bfr[ni] = *(const short8*)&lB[cur][(wn + ni * 16 + c15) * 32 + gs8];

    // WAR-safe: buf (st+D)%NBUF was last read at step st-1; those reads
    // completed (lgkm wait before MFMA) before each wave's step-st barrier.
    if (st + D < nst) stage((st + D) % NBUF, st + D);

    #pragma unroll
    for (int mi = 0; mi < MI; ++mi)
      #pragma unroll
      for (int ni = 0; ni < 2; ++ni)
        acc[mi][ni] = __builtin_amdgcn_mfma_f32_16x16x32_bf16(
            afr[mi], bfr[ni], acc[mi][ni], 0, 0, 0);
  }

  const int colb = n0 + wn + c15;
  const int rowb = m0 + wm + (lane >> 4) * 4;
  #pragma unroll
  for (int ni = 0; ni < 2; ++ni) {
    int col = colb + ni * 16;
    float bb = s.bias ? s.bias[col] : 0.f;
    float bu = 0.f, bvv = 0.f;
    if (s.epi == 1) { bu = s.bu[col]; bvv = s.bv[col]; }
    // fragment decompositions of col
    int hI = col >> 6, dI = col & 63;
    int kcd = (dI >> 5) & 1, gd = (dI >> 3) & 3, ed = dI & 7;   // d as k-dim
    int ntd = dI >> 4, c15d = dI & 15;                          // d as row-dim
    #pragma unroll
    for (int mi = 0; mi < MI; ++mi) {
      int row0 = rowb + mi * 16;
      size_t off0 = (size_t)row0 * 1024 + col;
      float v4[4];
      #pragma unroll
      for (int q = 0; q < 4; ++q) v4[q] = acc[mi][ni][q] + bb;
      switch (s.epi) {
        case 0:
          #pragma unroll
          for (int q = 0; q < 4; ++q) s.o16a[off0 + (size_t)q * 1024] = f2b(v4[q]);
          break;
        case 1:
          #pragma unroll
          for (int q = 0; q < 4; ++q) {
            int ri = row0 + q;
            size_t off = ((size_t)hI << 18) +
                         (((size_t)(((ri >> 4) * 2 + kcd) * 16 + (ri & 15)) * 4 + gd) << 3) + ed;
            s.o16a[off] = f2b((v4[q] + bu)  * 0.125f);
            s.o16b[off] = f2b((v4[q] + bvv) * 0.125f);
          }
          break;
        case 2:
          #pragma unroll
          for (int q = 0; q < 4; ++q) s.o16a[off0 + (size_t)q * 1024] = f2b(v4[q]);
          break;
        case 3:
          #pragma unroll
          for (int q = 0; q < 4; ++q) {
            size_t off = off0 + (size_t)q * 1024;
            float sg1 = 1.f / (1.f + __expf(-v4[q]));
            s.o16a[off] = f2b(sg1 * b2f(s.xB[off]));
          }
          break;
        case 4:
          #pragma unroll
          for (int q = 0; q < 4; ++q) {
            size_t off = off0 + (size_t)q * 1024;
            float z = 1.f / (1.f + __expf(-(b2f(s.zB[off]) - 2.f)));
            float r = (1.f - z) * s.xF[off] + z * tanhf(v4[q]);
            s.oF[off] = r;
            if (s.o16a) s.o16a[off] = f2b(r);
          }
          break;
        case 5:
          #pragma unroll
          for (int q = 0; q < 4; ++q) s.o16a[off0 + (size_t)q * 1024] = f2b(fmaxf(v4[q], 0.f));
          break;
        case 6: {
          // VT-frag: row0..row0+3 are consecutive j (same kc/g octet)
          int bI = row0 >> 9, j = row0 & 511;
          int kt = j >> 6, jj = j & 63;
          int kcj = jj >> 5, gj = (jj >> 3) & 3, e0 = jj & 7;
          size_t off = ((size_t)((bI * 16 + hI) * 8 + kt) << 12) +
                       (((size_t)((ntd * 2 + kcj) * 16 + c15d) * 4 + gj) << 3) + e0;
          uint2 o; o.x = pack2(v4[0], v4[1]); o.y = pack2(v4[2], v4[3]);
          *(uint2*)(s.o16a + off) = o;
        } break;
        case 7:
          #pragma unroll
          for (int q = 0; q < 4; ++q) {
            int rj = row0 + q;
            int bI = rj >> 9, kt = (rj >> 6) & 7, jr = rj & 63;
            size_t off = ((size_t)((bI * 16 + hI) * 8 + kt) << 12) +
                         (((size_t)(((jr >> 4) * 2 + kcd) * 16 + (jr & 15)) * 4 + gd) << 3) + ed;
            s.o16a[off] = f2b(v4[q]);
          }
          break;
        case 8:
          #pragma unroll
          for (int q = 0; q < 4; ++q) {
            int t = row0 + q;
            size_t off = ((size_t)hI << 14) +
                         (((size_t)(((t >> 4) * 2 + kcd) * 16 + (t & 15)) * 4 + gd) << 3) + ed;
            s.o16a[off] = f2b(v4[q]);
          }
          break;
      }
    }
  }
}

// ---------------------------------------------------------------------------
// LayerNorm over rows of 1024, fp32 in -> bf16 out (+ optional raw bf16 copy)
// Fused q/k variant: blockIdx.x in [0,8192): rows 0..4095 = x1, 4096.. = x2.
// ---------------------------------------------------------------------------
__global__ __launch_bounds__(256) void ln_kernel(
    const float* __restrict__ x1, const float* __restrict__ x2,
    const float* __restrict__ g, const float* __restrict__ bb,
    u16* __restrict__ out1p, u16* __restrict__ out2p,
    u16* __restrict__ raw1)
{
  const int blk = blockIdx.x, t = threadIdx.x;
  const int row = blk & 4095;
  const bool second = blk >= 4096;
  const float* x = second ? x2 : x1;
  u16* out = second ? out2p : out1p;
  float4 xv = ((const float4*)x)[(size_t)row * 256 + t];
  float s  = xv.x + xv.y + xv.z + xv.w;
  float s2 = xv.x * xv.x + xv.y * xv.y + xv.z * xv.z + xv.w * xv.w;
  s = wred_sum(s); s2 = wred_sum(s2);
  __shared__ float sh[8];
  int wid = t >> 6, lane = t & 63;
  if (lane == 0) { sh[wid] = s; sh[4 + wid] = s2; }
  __syncthreads();
  s  = sh[0] + sh[1] + sh[2] + sh[3];
  s2 = sh[4] + sh[5] + sh[6] + sh[7];
  float mean = s * (1.f / 1024.f);
  float var  = s2 * (1.f / 1024.f) - mean * mean;
  float rstd = rsqrtf(var + 1e-5f);
  float4 gv = ((const float4*)g)[t];
  float4 bv = ((const float4*)bb)[t];
  uint2 o;
  o.x = pack2((xv.x - mean) * rstd * gv.x + bv.x,
              (xv.y - mean) * rstd * gv.y + bv.y);
  o.y = pack2((xv.z - mean) * rstd * gv.z + bv.z,
              (xv.w - mean) * rstd * gv.w + bv.w);
  *(uint2*)&out[(size_t)row * 1024 + t * 4] = o;
  if (!second && raw1) {
    uint2 o2; o2.x = pack2(xv.x, xv.y); o2.y = pack2(xv.z, xv.w);
    *(uint2*)&raw1[(size_t)row * 1024 + t * 4] = o2;
  }
}

__global__ __launch_bounds__(256) void posenc_kernel(u16* __restrict__ out)
{
  int idx = blockIdx.x * 256 + threadIdx.x;   // 0..262143
  int i = idx >> 9, f = idx & 511;
  float pos = (float)(Sc - 1 - i);
  float invf = expf((float)f * -0.017988946039016f);
  float ang = pos * invf;
  out[(size_t)i * 1024 + f]       = f2b(sinf(ang));
  out[(size_t)i * 1024 + 512 + f] = f2b(cosf(ang));
}

// ---------------------------------------------------------------------------
// MFMA flash attention, balanced q-tile pairing {x, 7-x}, double-buffered
// async LDS staging of fragment-ordered K/VT tiles (T2-swizzled), qu/qv
// pre-scaled 1/8.
// ---------------------------------------------------------------------------
__global__ __launch_bounds__(256) void attn_mfma(
    const u16* __restrict__ quF, const u16* __restrict__ qvF,
    const u16* __restrict__ PK, const u16* __restrict__ PVT,
    const u16* __restrict__ RF, u16* __restrict__ out)
{
  __shared__ u16 lK[2][4096];
  __shared__ u16 lVT[2][4096];
  __shared__ u16 PW[4][16 * 72];

  const int tid = threadIdx.x;
  const int wave = tid >> 6, lane = tid & 63;
  const int g = lane >> 4, c15 = lane & 15;
  const int x = blockIdx.x;            // 0..3
  const int h = blockIdx.y, b = blockIdx.z;
  const int qA = x, qB = 7 - x;

  const size_t pkbase = (size_t)(b * 16 + h) << 15;   // 8 tiles * 4096 u16
  const size_t qhead  = (size_t)h << 18;
  const size_t rhead  = (size_t)h << 14;
  const size_t bh_off = ((size_t)b * Sc) * Ec + h * Dc;
  const int fchunk  = (c15 * 4 + g) * 8;                          // global frag offset
  const int fchunkS = (c15 * 4 + (g ^ ((c15 >> 1) & 3))) * 8;     // LDS swizzled read
  const int src8 = (tid ^ ((tid >> 3) & 3)) * 8;                  // swizzled stage src

  u16* pw = PW[wave];

  auto stage = [&](int buf, int kt) {
    const u16* ks = PK  + pkbase + ((size_t)kt << 12);
    const u16* vs = PVT + pkbase + ((size_t)kt << 12);
    gload16(ks + src8,        &lK[buf][tid * 8]);
    gload16(ks + 2048 + src8, &lK[buf][2048 + tid * 8]);
    gload16(vs + src8,        &lVT[buf][tid * 8]);
    gload16(vs + 2048 + src8, &lVT[buf][2048 + tid * 8]);
  };

  short8 qa[2], va[2];
  int i0w = qA * 64 + wave * 16;
  {
    int i16g = b * 32 + (i0w >> 4);
    #pragma unroll
    for (int kc = 0; kc < 2; ++kc) {
      size_t off = qhead + ((size_t)(i16g * 2 + kc) * 64) * 8 + fchunk;
      qa[kc] = *(const short8*)(quF + off);
      va[kc] = *(const short8*)(qvF + off);
    }
  }

  f32x4 oacc[4];
  #pragma unroll
  for (int t = 0; t < 4; ++t) oacc[t] = {0.f, 0.f, 0.f, 0.f};
  float m[4], l[4];
  #pragma unroll
  for (int q = 0; q < 4; ++q) { m[q] = -1e30f; l[q] = 0.f; }

  stage(0, 0);
  asm volatile("s_waitcnt vmcnt(0)" ::: "memory");
  __syncthreads();

  for (int s2 = 0; s2 < 9; ++s2) {
    const int buf = s2 & 1;
    const int kt = (s2 <= x) ? s2 : (s2 - x - 1);
    const int j0 = kt * 64;
    if (s2 < 8) {
      int ns = s2 + 1;
      stage(buf ^ 1, (ns <= x) ? ns : (ns - x - 1));
    }

    // ---- AC = (q+u)/8 K^T ----
    f32x4 ac[4];
    #pragma unroll
    for (int t = 0; t < 4; ++t) ac[t] = {0.f, 0.f, 0.f, 0.f};
    __builtin_amdgcn_s_setprio(1);
    #pragma unroll
    for (int kc = 0; kc < 2; ++kc)
      #pragma unroll
      for (int nt = 0; nt < 4; ++nt) {
        short8 kb = *(const short8*)&lK[buf][(nt * 2 + kc) * 512 + fchunkS];
        ac[nt] = __builtin_amdgcn_mfma_f32_16x16x32_bf16(qa[kc], kb, ac[nt], 0, 0, 0);
      }

    // ---- E band = (q+vb)/8 R^T ----
    const int t016 = (496 - i0w + j0) >> 4;
    f32x4 e5[5];
    #pragma unroll
    for (int t = 0; t < 5; ++t) e5[t] = {0.f, 0.f, 0.f, 0.f};
    #pragma unroll
    for (int kc = 0; kc < 2; ++kc)
      #pragma unroll
      for (int nt = 0; nt < 5; ++nt) {
        int t16 = t016 + nt; t16 = t16 > 31 ? 31 : t16;
        short8 rb = *(const short8*)(RF + rhead + (size_t)(t16 * 2 + kc) * 512 + fchunk);
        e5[nt] = __builtin_amdgcn_mfma_f32_16x16x32_bf16(va[kc], rb, e5[nt], 0, 0, 0);
      }
    __builtin_amdgcn_s_setprio(0);

    // ---- rel-shift rotate within 16-lane groups ----
    float rot[5][4];
    #pragma unroll
    for (int q = 0; q < 4; ++q) {
      int src = (lane & 48) | ((15 - (g * 4 + q) + c15) & 15);
      #pragma unroll
      for (int nt = 0; nt < 5; ++nt)
        rot[nt][q] = __shfl(e5[nt][q], src, 64);
    }

    // ---- combine + causal mask ----
    float s[4][4];
    #pragma unroll
    for (int ct = 0; ct < 4; ++ct) {
      int jcol = j0 + ct * 16 + c15;
      #pragma unroll
      for (int q = 0; q < 4; ++q) {
        int r = g * 4 + q;
        int u = 15 - r + c15;
        float bd = (u >> 4) ? rot[ct + 1][q] : rot[ct][q];
        float sv = ac[ct][q] + bd;
        s[ct][q] = (jcol <= i0w + r) ? sv : -1e30f;
      }
    }

    // ---- online softmax ----
    float mnew[4], csc[4];
    #pragma unroll
    for (int q = 0; q < 4; ++q) {
      float mx = fmaxf(fmaxf(s[0][q], s[1][q]), fmaxf(s[2][q], s[3][q]));
      #pragma unroll
      for (int o = 8; o; o >>= 1) mx = fmaxf(mx, __shfl_xor(mx, o, 64));
      mnew[q] = fmaxf(m[q], mx);
      csc[q] = __expf(m[q] - mnew[q]);
      m[q] = mnew[q];
    }
    float rs[4] = {0.f, 0.f, 0.f, 0.f};
    float p[4][4];
    #pragma unroll
    for (int ct = 0; ct < 4; ++ct)
      #pragma unroll
      for (int q = 0; q < 4; ++q) {
        p[ct][q] = __expf(s[ct][q] - mnew[q]);
        rs[q] += p[ct][q];
      }
    #pragma unroll
    for (int q = 0; q < 4; ++q) {
      float t = rs[q];
      #pragma unroll
      for (int o = 8; o; o >>= 1) t += __shfl_xor(t, o, 64);
      l[q] = l[q] * csc[q] + t;
      #pragma unroll
      for (int ct = 0; ct < 4; ++ct) oacc[ct][q] *= csc[q];
    }

    // ---- P -> bf16 via per-wave LDS transpose (wave-local) ----
    #pragma unroll
    for (int ct = 0; ct < 4; ++ct)
      #pragma unroll
      for (int q = 0; q < 4; ++q)
        pw[(g * 4 + q) * 72 + ct * 16 + c15] = f2b(p[ct][q]);

    // ---- PV from staged VT ----
    __builtin_amdgcn_s_setprio(1);
    #pragma unroll
    for (int kc = 0; kc < 2; ++kc) {
      short8 pa = *(const short8*)&pw[c15 * 72 + kc * 32 + g * 8];
      #pragma unroll
      for (int nt = 0; nt < 4; ++nt) {
        short8 vb8 = *(const short8*)&lVT[buf][(nt * 2 + kc) * 512 + fchunkS];
        oacc[nt] = __builtin_amdgcn_mfma_f32_16x16x32_bf16(pa, vb8, oacc[nt], 0, 0, 0);
      }
    }
    __builtin_amdgcn_s_setprio(0);

    // ---- phase switch: write q-tile A, reset for B ----
    if (s2 == x) {
      #pragma unroll
      for (int q = 0; q < 4; ++q) {
        float rl = 1.f / l[q];
        size_t ro = bh_off + (size_t)(i0w + g * 4 + q) * Ec;
        #pragma unroll
        for (int ct = 0; ct < 4; ++ct)
          out[ro + ct * 16 + c15] = f2b(oacc[ct][q] * rl);
      }
      i0w = qB * 64 + wave * 16;
      int i16g = b * 32 + (i0w >> 4);
      #pragma unroll
      for (int kc = 0; kc < 2; ++kc) {
        size_t off = qhead + ((size_t)(i16g * 2 + kc) * 64) * 8 + fchunk;
        qa[kc] = *(const short8*)(quF + off);
        va[kc] = *(const short8*)(qvF + off);
      }
      #pragma unroll
      for (int t = 0; t < 4; ++t) oacc[t] = {0.f, 0.f, 0.f, 0.f};
      #pragma unroll
      for (int q = 0; q < 4; ++q) { m[q] = -1e30f; l[q] = 0.f; }
    }

    asm volatile("s_waitcnt vmcnt(0)" ::: "memory");
    __syncthreads();
  }

  // ---- write q-tile B ----
  #pragma unroll
  for (int q = 0; q < 4; ++q) {
    float rl = 1.f / l[q];
    size_t ro = bh_off + (size_t)(i0w + g * 4 + q) * Ec;
    #pragma unroll
    for (int ct = 0; ct < 4; ++ct)
      out[ro + ct * 16 + c15] = f2b(oacc[ct][q] * rl);
  }
}

// ---------------------------------------------------------------------------
extern "C" void kernel_launch(void* const* d_in, const int* in_sizes, int n_in,
                              void* d_out, int out_size, void* d_ws, size_t ws_size,
                              hipStream_t stream) {
  (void)in_sizes; (void)n_in; (void)out_size; (void)ws_size;

  const float* query = (const float*)d_in[0];
  const float* key   = (const float*)d_in[1];
  const float* ln1_g = (const float*)d_in[4];
  const float* ln1_b = (const float*)d_in[5];
  const float* ln2_g = (const float*)d_in[6];
  const float* ln2_b = (const float*)d_in[7];
  const float* Wq = (const float*)d_in[8];   const float* bq = (const float*)d_in[9];
  const float* Wk = (const float*)d_in[10];  const float* bk = (const float*)d_in[11];
  const float* Wv = (const float*)d_in[12];  const float* bv_in = (const float*)d_in[13];
  const float* Wp = (const float*)d_in[14];
  const float* Wo = (const float*)d_in[15];  const float* bo = (const float*)d_in[16];
  const float* u_bias = (const float*)d_in[17];
  const float* v_bias = (const float*)d_in[18];
  const float* fc_W = (const float*)d_in[31]; const float* fc_b = (const float*)d_in[32];

  const size_t MB = 1ull << 20;
  char* ws = (char*)d_ws;
  u16* wb[18];
  for (int i = 0; i < 18; ++i) wb[i] = (u16*)(ws + (size_t)i * 2 * MB);
  u16*   normq16 = (u16*)(ws + 36 * MB);  // -> att16 -> rx16
  u16*   normk16 = (u16*)(ws + 44 * MB);  // -> Y16
  u16*   xq16    = (u16*)(ws + 52 * MB);  // -> ln2o16
  u16*   pos16   = (u16*)(ws + 60 * MB);
  u16*   rF16    = (u16*)(ws + 61 * MB);  // R fragment layout (512KB)
  u16*   quF16   = (u16*)(ws + 62 * MB);  // -> out116
  u16*   qvF16   = (u16*)(ws + 70 * MB);  // -> Ef16
  u16*   pk16    = (u16*)(ws + 78 * MB);  // \ -> tB16 (8MB)
  u16*   pvt16   = (u16*)(ws + 86 * MB);  // /
  float* out1    = (float*)(ws + 94 * MB);// 16MB
  u16*   att16   = normq16;
  u16*   Y16     = normk16;
  u16*   rx16    = normq16;
  u16*   out116  = quF16;
  u16*   Ef16    = qvF16;
  u16*   ln2o16  = xq16;
  u16*   tB16    = pk16;

  // --- weight conversion ---
  PtrBundle pb;
  const float* wsrc[18] = {Wq, Wk, Wv, Wp, Wo, fc_W,
                           (const float*)d_in[19], (const float*)d_in[20],
                           (const float*)d_in[21], (const float*)d_in[22],
                           (const float*)d_in[23], (const float*)d_in[24],
                           (const float*)d_in[25], (const float*)d_in[26],
                           (const float*)d_in[27], (const float*)d_in[28],
                           (const float*)d_in[29], (const float*)d_in[30]};
  for (int i = 0; i < 18; ++i) { pb.src[i] = wsrc[i]; pb.dst[i] = wb[i]; }
  cvtw_kernel<<<dim3(1024, 18), 256, 0, stream>>>(pb);

  // --- stage 1 (fused q/k LN; query LN also emits raw bf16 copy -> xq16) ---
  ln_kernel<<<8192, 256, 0, stream>>>(query, key, ln1_g, ln1_b,
                                      normq16, normk16, xq16);
  posenc_kernel<<<1024, 256, 0, stream>>>(pos16);

  GemmSeg z{}; GemmDesc d;

  // --- QKV fused (grid 32x24, TM=TN=128, 512 thr) ---
  d.seg[0] = z; d.seg[0].A1 = normq16; d.seg[0].W1 = wb[0]; d.seg[0].bias = bq;
  d.seg[0].bu = u_bias; d.seg[0].bv = v_bias;
  d.seg[0].o16a = quF16; d.seg[0].o16b = qvF16; d.seg[0].epi = 1;
  d.seg[1] = z; d.seg[1].A1 = normk16; d.seg[1].W1 = wb[1]; d.seg[1].bias = bk;
  d.seg[1].o16a = pk16; d.seg[1].epi = 7;
  d.seg[2] = z; d.seg[2].A1 = normk16; d.seg[2].W1 = wb[2]; d.seg[2].bias = bv_in;
  d.seg[2].o16a = pvt16; d.seg[2].epi = 6;
  gemm_f<128, 128><<<dim3(32, 24), 512, 0, stream>>>(d);

  // --- Wp (M=512, TM=TN=64, grid 8x16) -> R fragment layout ---
  d.seg[0] = z; d.seg[0].A1 = pos16; d.seg[0].W1 = wb[3];
  d.seg[0].o16a = rF16; d.seg[0].epi = 8;
  gemm_f<64, 64><<<dim3(8, 16), 256, 0, stream>>>(d);

  // --- attention (balanced pairing, grid 4x16x8) ---
  attn_mfma<<<dim3(4, 16, 8), 256, 0, stream>>>(quF16, qvF16, pk16, pvt16,
                                                rF16, att16);

  // --- Wo (TM=TN=64, grid 64x16 -> 4 blocks/CU) ---
  d.seg[0] = z; d.seg[0].A1 = att16; d.seg[0].W1 = wb[4]; d.seg[0].bias = bo;
  d.seg[0].o16a = Y16; d.seg[0].epi = 0;
  gemm_f<64, 64><<<dim3(64, 16), 256, 0, stream>>>(d);

  // --- gate1 r+z (dual-K, TM=TN=128, 512 thr, grid 32x16) ---
  d.seg[0] = z; d.seg[0].A1 = Y16; d.seg[0].A2 = xq16;
  d.seg[0].W1 = wb[6]; d.seg[0].W2 = wb[7];
  d.seg[0].xB = xq16; d.seg[0].o16a = rx16; d.seg[0].epi = 3;
  d.seg[1] = z; d.seg[1].A1 = Y16; d.seg[1].A2 = xq16;
  d.seg[1].W1 = wb[8]; d.seg[1].W2 = wb[9];
  d.seg[1].o16a = tB16; d.seg[1].epi = 2;
  gemm_f<128, 128><<<dim3(32, 16), 512, 0, stream>>>(d);

  // --- gate1 g + combine (dual-K, TM=TN=64, grid 64x16 -> 4 blocks/CU) ---
  d.seg[0] = z; d.seg[0].A1 = Y16; d.seg[0].A2 = rx16;
  d.seg[0].W1 = wb[10]; d.seg[0].W2 = wb[11];
  d.seg[0].xF = query; d.seg[0].zB = tB16;
  d.seg[0].oF = out1; d.seg[0].o16a = out116; d.seg[0].epi = 4;
  gemm_f<64, 64><<<dim3(64, 16), 256, 0, stream>>>(d);

  // --- FFN ---
  ln_kernel<<<4096, 256, 0, stream>>>(out1, nullptr, ln2_g, ln2_b,
                                      ln2o16, nullptr, nullptr);
  d.seg[0] = z; d.seg[0].A1 = ln2o16; d.seg[0].W1 = wb[5]; d.seg[0].bias = fc_b;
  d.seg[0].o16a = Ef16; d.seg[0].epi = 5;
  gemm_f<64, 64><<<dim3(64, 16), 256, 0, stream>>>(d);

  // --- gate2 r+z (dual-K, TM=TN=128, 512 thr, grid 32x16) ---
  d.seg[0] = z; d.seg[0].A1 = Ef16; d.seg[0].A2 = out116;
  d.seg[0].W1 = wb[12]; d.seg[0].W2 = wb[13];
  d.seg[0].xB = out116; d.seg[0].o16a = rx16; d.seg[0].epi = 3;
  d.seg[1] = z; d.seg[1].A1 = Ef16; d.seg[1].A2 = out116;
  d.seg[1].W1 = wb[14]; d.seg[1].W2 = wb[15];
  d.seg[1].o16a = tB16; d.seg[1].epi = 2;
  gemm_f<128, 128><<<dim3(32, 16), 512, 0, stream>>>(d);

  // --- gate2 g + final combine (dual-K, TM=TN=64, grid 64x16) ---
  d.seg[0] = z; d.seg[0].A1 = Ef16; d.seg[0].A2 = rx16;
  d.seg[0].W1 = wb[16]; d.seg[0].W2 = wb[17];
  d.seg[0].xF = out1; d.seg[0].zB = tB16;
  d.seg[0].oF = (float*)d_out; d.seg[0].epi = 4;
  gemm_f<64, 64><<<dim3(64, 16), 256, 0, stream>>>(d);
}